// Round 4
// baseline (326.750 us; speedup 1.0000x reference)
//
#include <hip/hip_runtime.h>
#include <stdint.h>

// LinearAttend: q,k,v (4,8,64,8192) fp32.
//   out[j][s] = sum_i (C[i][j]*0.125/rowsum[i]) * exp(q[i][s])/colsum[s]
//   C[i][j]   = sum_s exp(k[i][s]) * v[j][s]
// Split-bf16 MFMA (x = hi + lo, 3 MFMAs), error ~2^-18 relative.
//
// v4 (resubmit; round-3 bench was a container/infra failure, no verdict):
// ctx is TLP-maximized (r2 post-mortem: VGPR=64 proves the compiler sank
// the dbuf loads -> shallow ILP; grid capped waves at 4/SIMD; three
// different ctx structures all ~2 TB/s delivered => latency-bound on TLP).
// 512-thr blocks, 8 waves, 1x2 tiles/wave -> 8192 waves = 8/SIMD.
// reduce_kernel eliminated: ctx atomicAdds partials into C[h][4096] +
// R[h][64] (fp32 atomics, device scope); out_kernel normalizes on load.

typedef __attribute__((ext_vector_type(8))) short bf16x8;
typedef __attribute__((ext_vector_type(4))) float floatx4;

constexpr int D = 64, S = 8192, HEADS = 32;
constexpr int NC = 32;               // ctx chunks per head
constexpr int CHUNK = S / NC;        // 256 s per ctx block
constexpr int NK = CHUNK / 32;       // 8 K-steps of 32 cols

__device__ __forceinline__ short bf16_rn(float x) {
    unsigned u = __builtin_bit_cast(unsigned, x);
    return (short)((u + 0x8000u) >> 16);
}
__device__ __forceinline__ float bf16_f(short h) {
    unsigned u = ((unsigned)(unsigned short)h) << 16;
    return __builtin_bit_cast(float, u);
}
__device__ __forceinline__ void split8(const float* x, bf16x8& hi, bf16x8& lo) {
#pragma unroll
    for (int e = 0; e < 8; ++e) {
        short h = bf16_rn(x[e]);
        hi[e] = h;
        lo[e] = bf16_rn(x[e] - bf16_f(h));
    }
}

// ---------------------------------------------------------------- ctx ----
// Grid (32 heads, 32 chunks) x 512 (8 waves). Wave w: mt = w>>1 owns A-rows
// mt*16+m; nt0 = (w&1)*2 owns B-row-sets nt0, nt0+1. Per K-step a lane
// loads 1 A-fragment + 2 B-fragments (8 contiguous floats each = 6 dwordx4),
// exp+split A, split B x2, 6 MFMAs into 2 accumulators. Small live state ->
// honest 64 VGPR -> 8 waves/SIMD. Epilogue: device atomicAdd into C, R.
__global__ __launch_bounds__(512, 8) void ctx_kernel(
    const float* __restrict__ K, const float* __restrict__ V,
    float* __restrict__ C,       // [h][4096] fragment-layout accumulators
    float* __restrict__ R)       // [h][64] rowsums
{
    const int h = blockIdx.x, c = blockIdx.y;
    const int wave = threadIdx.x >> 6, lane = threadIdx.x & 63;
    const int m = lane & 15, quad = lane >> 4;
    const int mt = wave >> 1, nt0 = (wave & 1) << 1;

    const float* pa = K + (size_t)h * D * S + (size_t)(mt * 16 + m) * S
                    + c * CHUNK + quad * 8;
    const float* pb0 = V + (size_t)h * D * S + (size_t)(nt0 * 16 + m) * S
                     + c * CHUNK + quad * 8;
    const float* pb1 = pb0 + (size_t)16 * S;

    floatx4 acc[2];
    acc[0] = (floatx4){0.f, 0.f, 0.f, 0.f};
    acc[1] = (floatx4){0.f, 0.f, 0.f, 0.f};
    float rs = 0.f;

    float ka0[8], v0a[8], v1a[8], ka1[8], v0b[8], v1b[8];

    auto loadstep = [&](float* ka, float* va0, float* va1, int kk) {
        const int off = kk * 32;
        *(float4*)&ka[0]  = *(const float4*)(pa + off);
        *(float4*)&ka[4]  = *(const float4*)(pa + off + 4);
        *(float4*)&va0[0] = *(const float4*)(pb0 + off);
        *(float4*)&va0[4] = *(const float4*)(pb0 + off + 4);
        *(float4*)&va1[0] = *(const float4*)(pb1 + off);
        *(float4*)&va1[4] = *(const float4*)(pb1 + off + 4);
    };

    auto compute = [&](float* ka, float* va0, float* va1) {
        float ex[8];
#pragma unroll
        for (int e = 0; e < 8; ++e) {
            ex[e] = __expf(ka[e]);
            rs += ex[e];
        }
        bf16x8 ah, al, b0h, b0l, b1h, b1l;
        split8(ex, ah, al);
        split8(va0, b0h, b0l);
        split8(va1, b1h, b1l);
        acc[0] = __builtin_amdgcn_mfma_f32_16x16x32_bf16(ah, b0h, acc[0], 0, 0, 0);
        acc[0] = __builtin_amdgcn_mfma_f32_16x16x32_bf16(ah, b0l, acc[0], 0, 0, 0);
        acc[0] = __builtin_amdgcn_mfma_f32_16x16x32_bf16(al, b0h, acc[0], 0, 0, 0);
        acc[1] = __builtin_amdgcn_mfma_f32_16x16x32_bf16(ah, b1h, acc[1], 0, 0, 0);
        acc[1] = __builtin_amdgcn_mfma_f32_16x16x32_bf16(ah, b1l, acc[1], 0, 0, 0);
        acc[1] = __builtin_amdgcn_mfma_f32_16x16x32_bf16(al, b1h, acc[1], 0, 0, 0);
    };

    loadstep(ka0, v0a, v1a, 0);
#pragma unroll
    for (int kk = 0; kk < NK; kk += 2) {
        if (kk + 1 < NK) loadstep(ka1, v0b, v1b, kk + 1);
        compute(ka0, v0a, v1a);
        if (kk + 2 < NK) loadstep(ka0, v0a, v1a, kk + 2);
        compute(ka1, v0b, v1b);
    }

    // rowsum: butterfly over quad bits -> row totals at all lanes
    rs += __shfl_xor(rs, 16, 64);
    rs += __shfl_xor(rs, 32, 64);

    float* Cb = C + ((size_t)h << 12);
#pragma unroll
    for (int x = 0; x < 2; ++x) {
        const int tile = mt * 4 + nt0 + x;
#pragma unroll
        for (int r = 0; r < 4; ++r)
            atomicAdd(&Cb[(tile * 4 + r) * 64 + lane], acc[x][r]);
    }
    if ((wave & 1) == 0 && lane < 16)
        atomicAdd(&R[(h << 6) + mt * 16 + lane], rs);
}

// ---------------------------------------------------------------- out ----
// Grid (32 heads, 32) x 256 (4 waves -> 4096 waves, 2x TLP of r2). Wave
// covers 64 s (4 iters of 16). Prologue: invr[i] = 0.125/R[i] via LDS;
// A-frags gathered from C's fragment layout ((i,j) at
// (((i>>4)*4+jt)*4 + (i&3))*64 + (((i&15)>>2)<<4) + m), scaled, split once.
// B = exp(q) columns; colsum via quad butterfly; divide at epilogue.
__global__ __launch_bounds__(256, 4) void out_kernel(
    const float* __restrict__ Q, const float* __restrict__ C,
    const float* __restrict__ R, float* __restrict__ Out)
{
    __shared__ float invr[D];
    const int h = blockIdx.x;
    const int wave = threadIdx.x >> 6, lane = threadIdx.x & 63;
    const int m = lane & 15, quad = lane >> 4;
    const int sbase = (blockIdx.y * 4 + wave) * 64;

    if (threadIdx.x < D)
        invr[threadIdx.x] = 0.125f / R[(h << 6) + threadIdx.x];
    __syncthreads();

    bf16x8 Ah[4][2], Al[4][2];
    const float* Cb = C + ((size_t)h << 12);
#pragma unroll
    for (int jt = 0; jt < 4; ++jt)
#pragma unroll
        for (int kk = 0; kk < 2; ++kk) {
            float a[8];
#pragma unroll
            for (int e = 0; e < 8; ++e) {
                const int i = kk * 32 + quad * 8 + e;
                const int idx = (((i >> 4) * 4 + jt) * 4 + (i & 3)) * 64
                              + (((i & 15) >> 2) << 4) + m;
                a[e] = Cb[idx] * invr[i];
            }
            split8(a, Ah[jt][kk], Al[jt][kk]);
        }

    const float* Qb = Q + (size_t)h * D * S;
    float* Ob = Out + (size_t)h * D * S;

    for (int it = 0; it < 4; ++it) {
        const int scol = sbase + it * 16 + m;
        float e[16];
        float cs = 0.f;
#pragma unroll
        for (int kk = 0; kk < 2; ++kk)
#pragma unroll
            for (int j2 = 0; j2 < 8; ++j2) {
                const float qv = Qb[(size_t)(kk * 32 + quad * 8 + j2) * S + scol];
                const float ev = __expf(qv);
                e[kk * 8 + j2] = ev;
                cs += ev;
            }
        cs += __shfl_xor(cs, 16, 64);
        cs += __shfl_xor(cs, 32, 64);
        const float inv = 1.0f / cs;

        bf16x8 Bh[2], Bl[2];
        split8(&e[0], Bh[0], Bl[0]);
        split8(&e[8], Bh[1], Bl[1]);

#pragma unroll
        for (int jt = 0; jt < 4; ++jt) {
            floatx4 a = (floatx4){0.f, 0.f, 0.f, 0.f};
#pragma unroll
            for (int kk = 0; kk < 2; ++kk) {
                a = __builtin_amdgcn_mfma_f32_16x16x32_bf16(Ah[jt][kk], Bh[kk], a, 0, 0, 0);
                a = __builtin_amdgcn_mfma_f32_16x16x32_bf16(Ah[jt][kk], Bl[kk], a, 0, 0, 0);
                a = __builtin_amdgcn_mfma_f32_16x16x32_bf16(Al[jt][kk], Bh[kk], a, 0, 0, 0);
            }
#pragma unroll
            for (int r = 0; r < 4; ++r)
                Ob[(size_t)(jt * 16 + quad * 4 + r) * S + scol] = a[r] * inv;
        }
    }
}

extern "C" void kernel_launch(void* const* d_in, const int* in_sizes, int n_in,
                              void* d_out, int out_size, void* d_ws, size_t ws_size,
                              hipStream_t stream) {
    const float* q = (const float*)d_in[0];
    const float* k = (const float*)d_in[1];
    const float* v = (const float*)d_in[2];
    float* out = (float*)d_out;

    float* C = (float*)d_ws;                       // 32*4096*4 = 512 KB
    float* R = C + (size_t)HEADS * 4096;           // 32*64*4  =   8 KB

    hipMemsetAsync(d_ws, 0, (size_t)(HEADS * 4096 + HEADS * 64) * sizeof(float),
                   stream);
    ctx_kernel<<<dim3(HEADS, NC), 512, 0, stream>>>(k, v, C, R);
    out_kernel<<<dim3(HEADS, 32), 256, 0, stream>>>(q, C, R, out);
}

// Round 5
// 311.555 us; speedup vs baseline: 1.0488x; 1.0488x over previous
//
#include <hip/hip_runtime.h>
#include <stdint.h>

// LinearAttend: q,k,v (4,8,64,8192) fp32.
//   out[j][s] = sum_i (C[i][j]*0.125/rowsum[i]) * exp(q[i][s])/colsum[s]
//   C[i][j]   = sum_s exp(k[i][s]) * v[j][s]
// Split-bf16 MFMA (x = hi + lo, 3 MFMAs), error ~2^-18 relative.
//
// v5: out_kernel rewritten on mfma_f32_32x32x16_bf16. r4 counters showed
// out at 114us with 341 MB HBM traffic vs 134 MB ideal: the 16x16 fragment
// layout makes every Q-read / Out-write row segment 64 B (lane&15 cols),
// i.e. half a 128 B line -> partial-line fills + RMW stores. The 32x32
// layout puts cols at lane&31 = 128 B full-line segments for both loads
// and stores. ctx_kernel unchanged (v4 atomics; its true duration becomes
// visible next round once out drops out of the way).

typedef __attribute__((ext_vector_type(8))) short bf16x8;
typedef __attribute__((ext_vector_type(4))) float floatx4;
typedef __attribute__((ext_vector_type(16))) float floatx16;

constexpr int D = 64, S = 8192, HEADS = 32;
constexpr int NC = 32;               // ctx chunks per head
constexpr int CHUNK = S / NC;        // 256 s per ctx block
constexpr int NK = CHUNK / 32;       // 8 K-steps of 32 cols

__device__ __forceinline__ short bf16_rn(float x) {
    unsigned u = __builtin_bit_cast(unsigned, x);
    return (short)((u + 0x8000u) >> 16);
}
__device__ __forceinline__ float bf16_f(short h) {
    unsigned u = ((unsigned)(unsigned short)h) << 16;
    return __builtin_bit_cast(float, u);
}
__device__ __forceinline__ void split8(const float* x, bf16x8& hi, bf16x8& lo) {
#pragma unroll
    for (int e = 0; e < 8; ++e) {
        short h = bf16_rn(x[e]);
        hi[e] = h;
        lo[e] = bf16_rn(x[e] - bf16_f(h));
    }
}

// ---------------------------------------------------------------- ctx ----
// Grid (32 heads, 32 chunks) x 512 (8 waves). Wave w: mt = w>>1 owns A-rows
// mt*16+m; nt0 = (w&1)*2 owns B-row-sets nt0, nt0+1. Per K-step a lane
// loads 1 A-fragment + 2 B-fragments (8 contiguous floats each = 6 dwordx4),
// exp+split A, split B x2, 6 MFMAs into 2 accumulators. Small live state ->
// honest 64 VGPR -> 8 waves/SIMD. Epilogue: device atomicAdd into C, R.
__global__ __launch_bounds__(512, 8) void ctx_kernel(
    const float* __restrict__ K, const float* __restrict__ V,
    float* __restrict__ C,       // [h][4096] fragment-layout accumulators
    float* __restrict__ R)       // [h][64] rowsums
{
    const int h = blockIdx.x, c = blockIdx.y;
    const int wave = threadIdx.x >> 6, lane = threadIdx.x & 63;
    const int m = lane & 15, quad = lane >> 4;
    const int mt = wave >> 1, nt0 = (wave & 1) << 1;

    const float* pa = K + (size_t)h * D * S + (size_t)(mt * 16 + m) * S
                    + c * CHUNK + quad * 8;
    const float* pb0 = V + (size_t)h * D * S + (size_t)(nt0 * 16 + m) * S
                     + c * CHUNK + quad * 8;
    const float* pb1 = pb0 + (size_t)16 * S;

    floatx4 acc[2];
    acc[0] = (floatx4){0.f, 0.f, 0.f, 0.f};
    acc[1] = (floatx4){0.f, 0.f, 0.f, 0.f};
    float rs = 0.f;

    float ka0[8], v0a[8], v1a[8], ka1[8], v0b[8], v1b[8];

    auto loadstep = [&](float* ka, float* va0, float* va1, int kk) {
        const int off = kk * 32;
        *(float4*)&ka[0]  = *(const float4*)(pa + off);
        *(float4*)&ka[4]  = *(const float4*)(pa + off + 4);
        *(float4*)&va0[0] = *(const float4*)(pb0 + off);
        *(float4*)&va0[4] = *(const float4*)(pb0 + off + 4);
        *(float4*)&va1[0] = *(const float4*)(pb1 + off);
        *(float4*)&va1[4] = *(const float4*)(pb1 + off + 4);
    };

    auto compute = [&](float* ka, float* va0, float* va1) {
        float ex[8];
#pragma unroll
        for (int e = 0; e < 8; ++e) {
            ex[e] = __expf(ka[e]);
            rs += ex[e];
        }
        bf16x8 ah, al, b0h, b0l, b1h, b1l;
        split8(ex, ah, al);
        split8(va0, b0h, b0l);
        split8(va1, b1h, b1l);
        acc[0] = __builtin_amdgcn_mfma_f32_16x16x32_bf16(ah, b0h, acc[0], 0, 0, 0);
        acc[0] = __builtin_amdgcn_mfma_f32_16x16x32_bf16(ah, b0l, acc[0], 0, 0, 0);
        acc[0] = __builtin_amdgcn_mfma_f32_16x16x32_bf16(al, b0h, acc[0], 0, 0, 0);
        acc[1] = __builtin_amdgcn_mfma_f32_16x16x32_bf16(ah, b1h, acc[1], 0, 0, 0);
        acc[1] = __builtin_amdgcn_mfma_f32_16x16x32_bf16(ah, b1l, acc[1], 0, 0, 0);
        acc[1] = __builtin_amdgcn_mfma_f32_16x16x32_bf16(al, b1h, acc[1], 0, 0, 0);
    };

    loadstep(ka0, v0a, v1a, 0);
#pragma unroll
    for (int kk = 0; kk < NK; kk += 2) {
        if (kk + 1 < NK) loadstep(ka1, v0b, v1b, kk + 1);
        compute(ka0, v0a, v1a);
        if (kk + 2 < NK) loadstep(ka0, v0a, v1a, kk + 2);
        compute(ka1, v0b, v1b);
    }

    // rowsum: butterfly over quad bits -> row totals at all lanes
    rs += __shfl_xor(rs, 16, 64);
    rs += __shfl_xor(rs, 32, 64);

    float* Cb = C + ((size_t)h << 12);
#pragma unroll
    for (int x = 0; x < 2; ++x) {
        const int tile = mt * 4 + nt0 + x;
#pragma unroll
        for (int r = 0; r < 4; ++r)
            atomicAdd(&Cb[(tile * 4 + r) * 64 + lane], acc[x][r]);
    }
    if ((wave & 1) == 0 && lane < 16)
        atomicAdd(&R[(h << 6) + mt * 16 + lane], rs);
}

// ---------------------------------------------------------------- out ----
// Grid (32 heads, 32) x 256 (4 waves). Wave covers 64 s (2 its of 32).
// 32x32x16 bf16 MFMA: A = Cn[j][i] (j = jt*32 + (lane&31),
// i = ks*16 + (lane>>5)*8 + e, blocked-K), B = exp(q)[i][scol]
// (scol = sbase + it*32 + (lane&31)). Every Q load / Out store instruction
// covers 2 rows x 128 B full lines. C/D: col = lane&31,
// row = (reg&3) + 8*(reg>>2) + 4*(lane>>5). colsum: lane sums its 32
// loaded i's, shfl_xor(32) adds the complementary half-wave rows.
__global__ __launch_bounds__(256, 4) void out_kernel(
    const float* __restrict__ Q, const float* __restrict__ C,
    const float* __restrict__ R, float* __restrict__ Out)
{
    __shared__ float invr[D];
    const int h = blockIdx.x;
    const int wave = threadIdx.x >> 6, lane = threadIdx.x & 63;
    const int n = lane & 31, hw = lane >> 5;
    const int sbase = (blockIdx.y * 4 + wave) * 64;

    if (threadIdx.x < D)
        invr[threadIdx.x] = 0.125f / R[(h << 6) + threadIdx.x];
    __syncthreads();

    // A fragments from C's 16x16 fragment layout:
    // element (i,j) lives at ((i>>4)*4 + (j>>4))*4 + (i&3))*64
    //                        + ((i&15)>>2)*16 + (j&15)
    bf16x8 Ah[2][4], Al[2][4];
    const float* Cb = C + ((size_t)h << 12);
    const int jq = n >> 4;          // (j>>4)&1
    const int jm = lane & 15;       // j&15
#pragma unroll
    for (int jt = 0; jt < 2; ++jt)
#pragma unroll
        for (int ks = 0; ks < 4; ++ks) {
            float a[8];
#pragma unroll
            for (int e = 0; e < 8; ++e) {
                const int i = ks * 16 + hw * 8 + e;       // i>>4 = ks
                const int tile = (ks << 2) + (jt << 1) + jq;
                const int idx = ((tile << 2) + (e & 3)) * 64
                              + ((hw * 2 + (e >> 2)) << 4) + jm;
                a[e] = Cb[idx] * invr[i];
            }
            split8(a, Ah[jt][ks], Al[jt][ks]);
        }

    const float* Qb = Q + (size_t)h * D * S;
    float* Ob = Out + (size_t)h * D * S;

    for (int it = 0; it < 2; ++it) {
        const int scol = sbase + it * 32 + n;
        floatx16 acc0, acc1;
#pragma unroll
        for (int r = 0; r < 16; ++r) { acc0[r] = 0.f; acc1[r] = 0.f; }
        float cs = 0.f;

#pragma unroll
        for (int ks = 0; ks < 4; ++ks) {
            float e8[8];
#pragma unroll
            for (int e = 0; e < 8; ++e) {
                const float qv = Qb[(size_t)(ks * 16 + hw * 8 + e) * S + scol];
                e8[e] = __expf(qv);
                cs += e8[e];
            }
            bf16x8 bh, bl;
            split8(e8, bh, bl);
            acc0 = __builtin_amdgcn_mfma_f32_32x32x16_bf16(Ah[0][ks], bh, acc0, 0, 0, 0);
            acc0 = __builtin_amdgcn_mfma_f32_32x32x16_bf16(Ah[0][ks], bl, acc0, 0, 0, 0);
            acc0 = __builtin_amdgcn_mfma_f32_32x32x16_bf16(Al[0][ks], bh, acc0, 0, 0, 0);
            acc1 = __builtin_amdgcn_mfma_f32_32x32x16_bf16(Ah[1][ks], bh, acc1, 0, 0, 0);
            acc1 = __builtin_amdgcn_mfma_f32_32x32x16_bf16(Ah[1][ks], bl, acc1, 0, 0, 0);
            acc1 = __builtin_amdgcn_mfma_f32_32x32x16_bf16(Al[1][ks], bh, acc1, 0, 0, 0);
        }

        cs += __shfl_xor(cs, 32, 64);   // full 64-row colsum
        const float inv = 1.0f / cs;

#pragma unroll
        for (int r = 0; r < 16; ++r) {
            const int jrow = (r & 3) + ((r >> 2) << 3) + (hw << 2);
            Ob[(size_t)jrow * S + scol] = acc0[r] * inv;
            Ob[(size_t)(32 + jrow) * S + scol] = acc1[r] * inv;
        }
    }
}

extern "C" void kernel_launch(void* const* d_in, const int* in_sizes, int n_in,
                              void* d_out, int out_size, void* d_ws, size_t ws_size,
                              hipStream_t stream) {
    const float* q = (const float*)d_in[0];
    const float* k = (const float*)d_in[1];
    const float* v = (const float*)d_in[2];
    float* out = (float*)d_out;

    float* C = (float*)d_ws;                       // 32*4096*4 = 512 KB
    float* R = C + (size_t)HEADS * 4096;           // 32*64*4  =   8 KB

    hipMemsetAsync(d_ws, 0, (size_t)(HEADS * 4096 + HEADS * 64) * sizeof(float),
                   stream);
    ctx_kernel<<<dim3(HEADS, NC), 512, 0, stream>>>(k, v, C, R);
    out_kernel<<<dim3(HEADS, 32), 256, 0, stream>>>(q, C, R, out);
}